// Round 1
// baseline (525.645 us; speedup 1.0000x reference)
//
#include <hip/hip_runtime.h>
#include <math.h>

#define NRES 256
#define CDIM 8
#define HNUM 12
#define CHD  16
#define PQN  4
#define PVN  8
#define CS   384

// ---------------------------------------------------------------------------
// Kernel 1: per-(c,n) projections q, k, v, q_pts, k_pts, v_pts
// ---------------------------------------------------------------------------
__global__ __launch_bounds__(256) void proj_kernel(
    const float* __restrict__ s, const float* __restrict__ rot,
    const float* __restrict__ trans,
    const float* __restrict__ wq, const float* __restrict__ bq,
    const float* __restrict__ wkv, const float* __restrict__ bkv,
    const float* __restrict__ wqp, const float* __restrict__ bqp,
    const float* __restrict__ wkvp, const float* __restrict__ bkvp,
    float* __restrict__ qo, float* __restrict__ ko, float* __restrict__ vo,
    float* __restrict__ qpo, float* __restrict__ kpo, float* __restrict__ vpo)
{
    const int row = blockIdx.x;      // c*256 + n
    const int tid = threadIdx.x;
    __shared__ float s_sh[CS];
    __shared__ float raw[432];

    for (int d = tid; d < CS; d += 256) s_sh[d] = s[row*CS + d];
    __syncthreads();

    // q: 192 cols
    for (int t = tid; t < 192; t += 256) {
        float acc = bq[t];
        for (int d = 0; d < CS; ++d) acc += s_sh[d] * wq[d*192 + t];
        qo[row*192 + t] = acc;
    }
    // kv: 384 cols -> split per head (first 16 = k, last 16 = v)
    for (int t = tid; t < 384; t += 256) {
        float acc = bkv[t];
        for (int d = 0; d < CS; ++d) acc += s_sh[d] * wkv[d*384 + t];
        int h = t >> 5, r = t & 31;
        if (r < 16) ko[row*192 + h*16 + r]        = acc;
        else        vo[row*192 + h*16 + (r-16)]   = acc;
    }
    // q_pts raw (144)
    for (int t = tid; t < 144; t += 256) {
        float acc = bqp[t];
        for (int d = 0; d < CS; ++d) acc += s_sh[d] * wqp[d*144 + t];
        raw[t] = acc;
    }
    __syncthreads();

    const float r00=rot[row*9+0], r01=rot[row*9+1], r02=rot[row*9+2];
    const float r10=rot[row*9+3], r11=rot[row*9+4], r12=rot[row*9+5];
    const float r20=rot[row*9+6], r21=rot[row*9+7], r22=rot[row*9+8];
    const float tx=trans[row*3+0], ty=trans[row*3+1], tz=trans[row*3+2];

    // assemble + transform q_pts: pts[p][xyz] = raw[xyz*48 + p], p = h*4+pp
    if (tid < 48) {
        const int p = tid;
        float x = raw[p], y = raw[48+p], z = raw[96+p];
        qpo[row*144 + p*3 + 0] = r00*x + r01*y + r02*z + tx;
        qpo[row*144 + p*3 + 1] = r10*x + r11*y + r12*z + ty;
        qpo[row*144 + p*3 + 2] = r20*x + r21*y + r22*z + tz;
    }
    __syncthreads();

    // kv_pts raw (432)
    for (int t = tid; t < 432; t += 256) {
        float acc = bkvp[t];
        for (int d = 0; d < CS; ++d) acc += s_sh[d] * wkvp[d*432 + t];
        raw[t] = acc;
    }
    __syncthreads();

    // pts[p][xyz] = raw[xyz*144 + p], p = h*12+pp; pp<4 -> k_pts, else v_pts
    if (tid < 144) {
        const int p = tid;
        float x = raw[p], y = raw[144+p], z = raw[288+p];
        float px = r00*x + r01*y + r02*z + tx;
        float py = r10*x + r11*y + r12*z + ty;
        float pz = r20*x + r21*y + r22*z + tz;
        int h = p / 12, pp = p - h*12;
        if (pp < 4) {
            int o = row*144 + (h*4+pp)*3;
            kpo[o+0]=px; kpo[o+1]=py; kpo[o+2]=pz;
        } else {
            int o = row*288 + (h*8+(pp-4))*3;
            vpo[o+0]=px; vpo[o+1]=py; vpo[o+2]=pz;
        }
    }
}

// ---------------------------------------------------------------------------
// Kernel 2: s_g = mean over C, LayerNorm, g_q/g_k projections  (per n)
// ---------------------------------------------------------------------------
__global__ __launch_bounds__(256) void gproj_kernel(
    const float* __restrict__ s, const float* __restrict__ g_gamma,
    const float* __restrict__ g_beta,
    const float* __restrict__ wgq, const float* __restrict__ bgq,
    const float* __restrict__ wgk, const float* __restrict__ bgk,
    float* __restrict__ gqo, float* __restrict__ gko)
{
    const int n = blockIdx.x;
    const int tid = threadIdx.x;
    __shared__ float sg[CS];
    __shared__ float red[256];

    for (int d = tid; d < CS; d += 256) {
        float acc = 0.f;
        for (int c = 0; c < CDIM; ++c) acc += s[(c*NRES+n)*CS + d];
        sg[d] = acc * (1.0f/CDIM);
    }
    __syncthreads();

    float lsum = 0.f;
    for (int d = tid; d < CS; d += 256) lsum += sg[d];
    red[tid] = lsum; __syncthreads();
    for (int st = 128; st > 0; st >>= 1) { if (tid < st) red[tid] += red[tid+st]; __syncthreads(); }
    const float mean = red[0] * (1.0f/CS);
    __syncthreads();

    float lvar = 0.f;
    for (int d = tid; d < CS; d += 256) { float df = sg[d]-mean; lvar += df*df; }
    red[tid] = lvar; __syncthreads();
    for (int st = 128; st > 0; st >>= 1) { if (tid < st) red[tid] += red[tid+st]; __syncthreads(); }
    const float var = red[0] * (1.0f/CS);
    __syncthreads();

    const float inv = rsqrtf(var + 1e-5f);
    for (int d = tid; d < CS; d += 256) sg[d] = (sg[d]-mean)*inv*g_gamma[d] + g_beta[d];
    __syncthreads();

    for (int t = tid; t < 192; t += 256) {
        float aq = bgq[t], ak = bgk[t];
        for (int d = 0; d < CS; ++d) {
            aq += sg[d]*wgq[d*192 + t];
            ak += sg[d]*wgk[d*192 + t];
        }
        gqo[n*192 + t] = aq;
        gko[n*192 + t] = ak;
    }
}

// ---------------------------------------------------------------------------
// Kernel 3: attention logits + softmax, writes `a` (output 1)
// block = (c*12+h)*256 + i, thread = j
// ---------------------------------------------------------------------------
__global__ __launch_bounds__(256) void attn_kernel(
    const float* __restrict__ q, const float* __restrict__ k,
    const float* __restrict__ q_pts, const float* __restrict__ k_pts,
    const float* __restrict__ g_q, const float* __restrict__ g_k,
    const float* __restrict__ trans, const float* __restrict__ mask,
    const float* __restrict__ head_weights, const float* __restrict__ wdist,
    const float* __restrict__ bdist, float* __restrict__ a_out)
{
    const int blk = blockIdx.x;
    const int i   = blk & 255;
    const int chh = blk >> 8;
    const int h   = chh % HNUM;
    const int c   = chh / HNUM;
    const int j   = threadIdx.x;

    __shared__ float q_sh[CHD];
    __shared__ float gq_sh[CHD];
    __shared__ float qp_sh[PQN*3];
    __shared__ float red[256];

    if (j < 16)      q_sh[j]      = q[((size_t)c*NRES+i)*192 + h*16 + j];
    else if (j < 32) gq_sh[j-16]  = g_q[i*192 + h*16 + (j-16)];
    else if (j < 44) qp_sh[j-32]  = q_pts[((size_t)c*NRES+i)*144 + h*12 + (j-32)];
    __syncthreads();

    float qk = 0.f;
    const float* krow = k + ((size_t)c*NRES + j)*192 + h*16;
    for (int d = 0; d < 16; ++d) qk += q_sh[d]*krow[d];

    float gdot = 0.f;
    const float* gkrow = g_k + j*192 + h*16;
    for (int d = 0; d < 16; ++d) gdot += gq_sh[d]*gkrow[d];

    float pt = 0.f;
    const float* kp = k_pts + ((size_t)c*NRES + j)*144 + h*12;
    for (int p = 0; p < 4; ++p) {
        float dx = qp_sh[p*3+0]-kp[p*3+0];
        float dy = qp_sh[p*3+1]-kp[p*3+1];
        float dz = qp_sh[p*3+2]-kp[p*3+2];
        pt += dx*dx + dy*dy + dz*dz;
    }
    const float hw = logf(1.0f + expf(head_weights[h])) * 0.13608276348795434f; // sqrt(1/54)
    const float scale = 0.14433756729740643f;                                    // sqrt(1/48)
    float logit = scale*(qk + gdot) - 0.5f*hw*pt;

    // mask bias
    logit += 100000.0f * (mask[c*NRES+i]*mask[c*NRES+j] - 1.0f);

    // distance bias: reference does db.reshape(B,C,H,N,N) -- RAW reshape.
    // target flat f = h*N*N + i*N + j, source coords: ii=f/3072, jj=(f%3072)/12, ho=f%12
    {
        int f   = h*65536 + i*256 + j;
        int ii  = f / 3072;
        int rem = f - ii*3072;
        int jj  = rem / 12;
        int ho  = rem - jj*12;
        float dx = trans[(c*NRES+ii)*3+0]-trans[(c*NRES+jj)*3+0];
        float dy = trans[(c*NRES+ii)*3+1]-trans[(c*NRES+jj)*3+1];
        float dz = trans[(c*NRES+ii)*3+2]-trans[(c*NRES+jj)*3+2];
        float dist = sqrtf(dx*dx + dy*dy + dz*dz);
        logit += dist*wdist[ho] + bdist[ho];
    }

    // softmax over j
    red[j] = logit; __syncthreads();
    for (int st = 128; st > 0; st >>= 1) { if (j < st) red[j] = fmaxf(red[j], red[j+st]); __syncthreads(); }
    const float m = red[0];
    __syncthreads();
    const float e = expf(logit - m);
    red[j] = e; __syncthreads();
    for (int st = 128; st > 0; st >>= 1) { if (j < st) red[j] += red[j+st]; __syncthreads(); }
    a_out[(size_t)blk*NRES + j] = e / red[0];
}

// ---------------------------------------------------------------------------
// Kernel 4: o = a@v, o_pt = a@v_pts, inverse rigid, norms, feat @ wout
// block = c*256 + i
// ---------------------------------------------------------------------------
__global__ __launch_bounds__(256) void out_kernel(
    const float* __restrict__ a, const float* __restrict__ v,
    const float* __restrict__ v_pts, const float* __restrict__ rot,
    const float* __restrict__ trans, const float* __restrict__ wout,
    const float* __restrict__ bout, float* __restrict__ out0)
{
    const int row = blockIdx.x;     // c*256 + i
    const int c   = row >> 8;
    const int i   = row & 255;
    const int tid = threadIdx.x;

    __shared__ float a_sh[HNUM*NRES];   // 12 KiB
    __shared__ float feat[576];
    __shared__ float opt_raw[288];

    for (int t = tid; t < HNUM*NRES; t += 256) {
        int h = t >> 8, j = t & 255;
        a_sh[t] = a[(((size_t)c*HNUM + h)*NRES + i)*NRES + j];
    }
    __syncthreads();

    // o: 192 outputs (h*16+d)
    for (int t = tid; t < 192; t += 256) {
        int h = t >> 4;
        float acc = 0.f;
        for (int j = 0; j < NRES; ++j) acc += a_sh[h*NRES+j] * v[((size_t)c*NRES+j)*192 + t];
        feat[t] = acc;
    }
    // o_pt raw: 288 outputs ((h*8+p)*3+xyz)
    for (int t = tid; t < 288; t += 256) {
        int h = t / 24;
        float acc = 0.f;
        for (int j = 0; j < NRES; ++j) acc += a_sh[h*NRES+j] * v_pts[((size_t)c*NRES+j)*288 + t];
        opt_raw[t] = acc;
    }
    __syncthreads();

    // inverse rigid transform + norms; feat layout: [o(192), x(96), y(96), z(96), norm(96)]
    if (tid < 96) {
        float x = opt_raw[tid*3+0] - trans[row*3+0];
        float y = opt_raw[tid*3+1] - trans[row*3+1];
        float z = opt_raw[tid*3+2] - trans[row*3+2];
        float rx = rot[row*9+0]*x + rot[row*9+3]*y + rot[row*9+6]*z;
        float ry = rot[row*9+1]*x + rot[row*9+4]*y + rot[row*9+7]*z;
        float rz = rot[row*9+2]*x + rot[row*9+5]*y + rot[row*9+8]*z;
        feat[192 + tid] = rx;
        feat[288 + tid] = ry;
        feat[384 + tid] = rz;
        feat[480 + tid] = sqrtf(rx*rx + ry*ry + rz*rz + 1e-8f);
    }
    __syncthreads();

    // out0 = feat @ wout + bout   (576 x 384)
    for (int t = tid; t < CS; t += 256) {
        float acc = bout[t];
        for (int f = 0; f < 576; ++f) acc += feat[f]*wout[f*CS + t];
        out0[(size_t)row*CS + t] = acc;
    }
}

// ---------------------------------------------------------------------------
extern "C" void kernel_launch(void* const* d_in, const int* in_sizes, int n_in,
                              void* d_out, int out_size, void* d_ws, size_t ws_size,
                              hipStream_t stream)
{
    const float* s     = (const float*)d_in[0];
    // d_in[1] = z (unused by the reference forward)
    const float* rot   = (const float*)d_in[2];
    const float* trans = (const float*)d_in[3];
    const float* mask  = (const float*)d_in[4];
    const float* wq    = (const float*)d_in[5];
    const float* bq    = (const float*)d_in[6];
    const float* wkv   = (const float*)d_in[7];
    const float* bkv   = (const float*)d_in[8];
    const float* g_gamma = (const float*)d_in[9];
    const float* g_beta  = (const float*)d_in[10];
    const float* wgq   = (const float*)d_in[11];
    const float* bgq   = (const float*)d_in[12];
    const float* wgk   = (const float*)d_in[13];
    const float* bgk   = (const float*)d_in[14];
    const float* wqp   = (const float*)d_in[15];
    const float* bqp   = (const float*)d_in[16];
    const float* wkvp  = (const float*)d_in[17];
    const float* bkvp  = (const float*)d_in[18];
    const float* head_weights = (const float*)d_in[19];
    const float* wdist = (const float*)d_in[20];
    const float* bdist = (const float*)d_in[21];
    const float* wout  = (const float*)d_in[22];
    const float* bout  = (const float*)d_in[23];

    float* ws     = (float*)d_ws;
    float* q_buf  = ws;                 // 2048*192
    float* k_buf  = ws + 393216;        // 2048*192
    float* v_buf  = ws + 786432;        // 2048*192
    float* qp_buf = ws + 1179648;       // 2048*144
    float* kp_buf = ws + 1474560;       // 2048*144
    float* vp_buf = ws + 1769472;       // 2048*288
    float* gq_buf = ws + 2359296;       // 256*192
    float* gk_buf = ws + 2408448;       // 256*192

    float* out0  = (float*)d_out;       // (1,8,256,384) = 786432
    float* a_out = out0 + 786432;       // (1,8,12,256,256) = 6291456

    proj_kernel<<<2048, 256, 0, stream>>>(s, rot, trans, wq, bq, wkv, bkv,
                                          wqp, bqp, wkvp, bkvp,
                                          q_buf, k_buf, v_buf, qp_buf, kp_buf, vp_buf);
    gproj_kernel<<<256, 256, 0, stream>>>(s, g_gamma, g_beta, wgq, bgq, wgk, bgk,
                                          gq_buf, gk_buf);
    attn_kernel<<<24576, 256, 0, stream>>>(q_buf, k_buf, qp_buf, kp_buf, gq_buf, gk_buf,
                                           trans, mask, head_weights, wdist, bdist, a_out);
    out_kernel<<<2048, 256, 0, stream>>>(a_out, v_buf, vp_buf, rot, trans, wout, bout, out0);
}